// Round 1
// baseline (327.402 us; speedup 1.0000x reference)
//
#include <hip/hip_runtime.h>
#include <math.h>

#define L_TOT 2304
#define C_TOT 128

// ---------------- DCT matrix (orthonormal DCT-II, 48x48) ----------------
__global__ void k_build_dct(float* __restrict__ D){
  int i = blockIdx.x * blockDim.x + threadIdx.x;
  if (i < 48 * 48){
    int k = i / 48, n = i - k * 48;
    double s = sqrt(2.0 / 48.0) * (k == 0 ? sqrt(0.5) : 1.0);
    D[i] = (float)(s * cos(M_PI * (n + 0.5) * (double)k / 48.0));
  }
}

// ---------------- 2D DCT: F = D * X * D^T per (b,c) image ----------------
__global__ __launch_bounds__(256) void k_dct2d(const float* __restrict__ X,
                                               const float* __restrict__ D,
                                               float* __restrict__ F){
  __shared__ float Xs[2304];
  __shared__ float Ts[2304];
  __shared__ float Ds[2304];
  const float* Xi = X + (size_t)blockIdx.x * 2304;
  float* Fi = F + (size_t)blockIdx.x * 2304;
  int tid = threadIdx.x;
  for (int i = tid; i < 2304; i += 256){ Xs[i] = Xi[i]; Ds[i] = D[i]; }
  __syncthreads();
  // T[m][w] = sum_n X[m][n] * D[w][n]
  for (int i = tid; i < 2304; i += 256){
    int m = i / 48, w = i - m * 48;
    float s = 0.f;
    #pragma unroll
    for (int n = 0; n < 48; n++) s += Xs[m * 48 + n] * Ds[w * 48 + n];
    Ts[i] = s;
  }
  __syncthreads();
  // F[h][w] = sum_m D[h][m] * T[m][w]
  for (int i = tid; i < 2304; i += 256){
    int h = i / 48, w = i - h * 48;
    float s = 0.f;
    #pragma unroll
    for (int m = 0; m < 48; m++) s += Ds[h * 48 + m] * Ts[m * 48 + w];
    Fi[i] = s;
  }
}

// ---------------- channel-mixing projection: Y[b,o,l] = sum_c W[o,c] X[b,c,l] + bias[o]
// grid: (L/64, 128/64, B), block 256, 64x64 tile, 4x4 per thread
__global__ __launch_bounds__(256) void k_proj(const float* __restrict__ W,
                                              const float* __restrict__ bias,
                                              const float* __restrict__ X,
                                              float* __restrict__ Y){
  const int L = L_TOT, C = C_TOT;
  int b = blockIdx.z;
  const float* Xb = X + (size_t)b * C * L;
  float* Yb = Y + (size_t)b * C * L;
  int n0 = blockIdx.x * 64, m0 = blockIdx.y * 64;
  __shared__ __align__(16) float As[16][64];   // As[k][m] = W[m0+m][k0+k]
  __shared__ __align__(16) float Bs[16][64];   // Bs[k][n] = X[k0+k][n0+n]
  int tid = threadIdx.x;
  int tx = tid & 15, ty = tid >> 4;
  float acc[4][4] = {};
  for (int k0 = 0; k0 < C; k0 += 16){
    __syncthreads();
    for (int i = tid; i < 1024; i += 256){
      int m = i & 63, k = i >> 6;
      As[k][m] = W[(size_t)(m0 + m) * C + k0 + k];
    }
    for (int i = tid; i < 1024; i += 256){
      int n = i & 63, k = i >> 6;
      Bs[k][n] = Xb[(size_t)(k0 + k) * L + n0 + n];
    }
    __syncthreads();
    #pragma unroll
    for (int k = 0; k < 16; k++){
      float4 a  = *(const float4*)&As[k][ty * 4];
      float4 bv = *(const float4*)&Bs[k][tx * 4];
      float av[4] = {a.x, a.y, a.z, a.w};
      float bb[4] = {bv.x, bv.y, bv.z, bv.w};
      #pragma unroll
      for (int i2 = 0; i2 < 4; i2++)
        #pragma unroll
        for (int j2 = 0; j2 < 4; j2++)
          acc[i2][j2] += av[i2] * bb[j2];
    }
  }
  #pragma unroll
  for (int i2 = 0; i2 < 4; i2++){
    int o = m0 + ty * 4 + i2;
    float bo = bias[o];
    float4 r;
    r.x = acc[i2][0] + bo; r.y = acc[i2][1] + bo;
    r.z = acc[i2][2] + bo; r.w = acc[i2][3] + bo;
    *(float4*)&Yb[(size_t)o * L + n0 + tx * 4] = r;
  }
}

// ---------------- attention: per (b,h): out = softmax(Q^T K * 0.25) V^T  ----------------
// Q,K,V layout (B, C, L): head slice rows c0..c0+15. Scores never materialized.
// Lanes own 4 consecutive s each (b128 LDS reads); 4 q-rows per thread in regs.
// No max-subtraction: scores are O(1) N(0,1)-ish, exp cannot overflow fp32.
__global__ __launch_bounds__(256, 2) void k_attn(const float* __restrict__ Q,
                                                 const float* __restrict__ K,
                                                 const float* __restrict__ V,
                                                 float* __restrict__ AO){
  const int L = L_TOT;
  int bh = blockIdx.y;
  int b = bh >> 3, h = bh & 7;
  int c0 = h * 16;
  const float* Qb = Q + ((size_t)b * C_TOT + c0) * L;
  const float* Kb = K + ((size_t)b * C_TOT + c0) * L;
  const float* Vb = V + ((size_t)b * C_TOT + c0) * L;
  int l0 = blockIdx.x * 16;
  int tid = threadIdx.x;
  int wv = tid >> 6, lane = tid & 63;

  __shared__ __align__(16) float smem[16384];  // 64 KB: Ks[16][512] | Vs[16][512]
  float* Ks = smem;
  float* Vs = smem + 8192;

  float q[4][16];
  float acc[4][16];
  float denom[4] = {0.f, 0.f, 0.f, 0.f};
  #pragma unroll
  for (int r = 0; r < 4; r++){
    int l = l0 + wv * 4 + r;
    #pragma unroll
    for (int d = 0; d < 16; d++){
      q[r][d] = Qb[(size_t)d * L + l] * 0.25f;  // fold scale = 1/sqrt(16)
      acc[r][d] = 0.f;
    }
  }

  for (int s0 = 0; s0 < L; s0 += 512){
    int cnt = (L - s0) < 512 ? (L - s0) : 512;   // 512,512,512,512,256
    int sh = (cnt == 512) ? 7 : 6;               // float4 per row
    int msk = (1 << sh) - 1;
    __syncthreads();
    for (int i = tid; i < (16 << sh); i += 256){
      int d = i >> sh, j = i & msk;
      ((float4*)Ks)[d * 128 + j] = ((const float4*)(Kb + (size_t)d * L + s0))[j];
      ((float4*)Vs)[d * 128 + j] = ((const float4*)(Vb + (size_t)d * L + s0))[j];
    }
    __syncthreads();
    int iters = cnt >> 8;   // 256 s per wave-iter (64 lanes x 4)
    for (int it = 0; it < iters; it++){
      int sl = it * 256 + lane * 4;
      float p[4][4];
      #pragma unroll
      for (int r = 0; r < 4; r++)
        #pragma unroll
        for (int j = 0; j < 4; j++) p[r][j] = 0.f;
      #pragma unroll
      for (int d = 0; d < 16; d++){
        float4 kd = *(const float4*)&Ks[d * 512 + sl];
        #pragma unroll
        for (int r = 0; r < 4; r++){
          p[r][0] += q[r][d] * kd.x; p[r][1] += q[r][d] * kd.y;
          p[r][2] += q[r][d] * kd.z; p[r][3] += q[r][d] * kd.w;
        }
      }
      #pragma unroll
      for (int r = 0; r < 4; r++)
        #pragma unroll
        for (int j = 0; j < 4; j++){
          p[r][j] = __expf(p[r][j]);
          denom[r] += p[r][j];
        }
      #pragma unroll
      for (int d = 0; d < 16; d++){
        float4 vd = *(const float4*)&Vs[d * 512 + sl];
        #pragma unroll
        for (int r = 0; r < 4; r++)
          acc[r][d] += p[r][0] * vd.x + p[r][1] * vd.y + p[r][2] * vd.z + p[r][3] * vd.w;
      }
    }
  }

  // ---- cross-lane combine via LDS reuse (2 phases to fit 64 KB) ----
  __syncthreads();
  float* red = smem;  // needs 9*16*64 = 9216 floats per phase <= 16384
  #pragma unroll
  for (int r = 0; r < 4; r++){
    int row = wv * 4 + r;
    #pragma unroll
    for (int d = 0; d < 8; d++)
      red[(d * 16 + row) * 64 + lane] = acc[r][d];
    red[(128 + row) * 64 + lane] = denom[r];
  }
  __syncthreads();
  int myd = tid & 15, myrow = tid >> 4;
  float dsum = 0.f;
  {
    int base = (128 + myrow) * 64;
    for (int j = 0; j < 64; j++) dsum += red[base + ((j + tid) & 63)];  // rotated: avoid bank hotspot
  }
  if (myd < 8){
    int base = (myd * 16 + myrow) * 64;
    float asum = 0.f;
    for (int j = 0; j < 64; j++) asum += red[base + ((j + tid) & 63)];
    AO[((size_t)b * C_TOT + c0 + myd) * L + l0 + myrow] = asum / dsum;
  }
  __syncthreads();
  #pragma unroll
  for (int r = 0; r < 4; r++){
    int row = wv * 4 + r;
    #pragma unroll
    for (int d = 8; d < 16; d++)
      red[((d - 8) * 16 + row) * 64 + lane] = acc[r][d];
  }
  __syncthreads();
  if (myd >= 8){
    int base = ((myd - 8) * 16 + myrow) * 64;
    float asum = 0.f;
    for (int j = 0; j < 64; j++) asum += red[base + ((j + tid) & 63)];
    AO[((size_t)b * C_TOT + c0 + myd) * L + l0 + myrow] = asum / dsum;
  }
}

extern "C" void kernel_launch(void* const* d_in, const int* in_sizes, int n_in,
                              void* d_out, int out_size, void* d_ws, size_t ws_size,
                              hipStream_t stream){
  const float* freq = (const float*)d_in[0];
  const float* spat = (const float*)d_in[1];
  const float* Wq = (const float*)d_in[2]; const float* bq = (const float*)d_in[3];
  const float* Wk = (const float*)d_in[4]; const float* bk = (const float*)d_in[5];
  const float* Wv = (const float*)d_in[6]; const float* bv = (const float*)d_in[7];
  const float* Wo = (const float*)d_in[8]; const float* bo = (const float*)d_in[9];
  float* ws = (float*)d_ws;

  // workspace layout (floats): D | SF | Q | K | V | AO  (~11.8 MB total)
  float* D  = ws;                 // 2304 (padded to 4096)
  float* SF = ws + 4096;          // 589824 each below
  float* Qb = ws + 593920;
  float* Kb = ws + 1183744;
  float* Vb = ws + 1773568;
  float* AO = ws + 2363392;
  float* out = (float*)d_out;

  k_build_dct<<<dim3(9), dim3(256), 0, stream>>>(D);
  k_dct2d<<<dim3(256), dim3(256), 0, stream>>>(spat, D, SF);
  k_proj<<<dim3(36, 2, 2), dim3(256), 0, stream>>>(Wq, bq, freq, Qb);
  k_proj<<<dim3(36, 2, 2), dim3(256), 0, stream>>>(Wk, bk, SF, Kb);
  k_proj<<<dim3(36, 2, 2), dim3(256), 0, stream>>>(Wv, bv, SF, Vb);
  k_attn<<<dim3(144, 16), dim3(256), 0, stream>>>(Qb, Kb, Vb, AO);
  k_proj<<<dim3(36, 2, 2), dim3(256), 0, stream>>>(Wo, bo, AO, out);
}

// Round 2
// 171.222 us; speedup vs baseline: 1.9122x; 1.9122x over previous
//
#include <hip/hip_runtime.h>
#include <math.h>

#define L_TOT 2304
#define C_TOT 128

typedef float v4f  __attribute__((ext_vector_type(4)));
typedef __bf16 v8bf __attribute__((ext_vector_type(8)));
typedef __bf16 v4bf __attribute__((ext_vector_type(4)));

#define MFMA_16x16x32_BF16(A, B, C) __builtin_amdgcn_mfma_f32_16x16x32_bf16((A), (B), (C), 0, 0, 0)

// ---------------- DCT matrix (orthonormal DCT-II, 48x48) ----------------
__global__ void k_build_dct(float* __restrict__ D){
  int i = blockIdx.x * blockDim.x + threadIdx.x;
  if (i < 48 * 48){
    int k = i / 48, n = i - k * 48;
    double s = sqrt(2.0 / 48.0) * (k == 0 ? sqrt(0.5) : 1.0);
    D[i] = (float)(s * cos(M_PI * (n + 0.5) * (double)k / 48.0));
  }
}

// ---------------- 2D DCT: F = D * X * D^T per (b,c) image ----------------
__global__ __launch_bounds__(256) void k_dct2d(const float* __restrict__ X,
                                               const float* __restrict__ D,
                                               float* __restrict__ F){
  __shared__ float Xs[2304];
  __shared__ float Ts[2304];
  __shared__ float Ds[2304];
  const float* Xi = X + (size_t)blockIdx.x * 2304;
  float* Fi = F + (size_t)blockIdx.x * 2304;
  int tid = threadIdx.x;
  for (int i = tid; i < 2304; i += 256){ Xs[i] = Xi[i]; Ds[i] = D[i]; }
  __syncthreads();
  for (int i = tid; i < 2304; i += 256){
    int m = i / 48, w = i - m * 48;
    float s = 0.f;
    #pragma unroll
    for (int n = 0; n < 48; n++) s += Xs[m * 48 + n] * Ds[w * 48 + n];
    Ts[i] = s;
  }
  __syncthreads();
  for (int i = tid; i < 2304; i += 256){
    int h = i / 48, w = i - h * 48;
    float s = 0.f;
    #pragma unroll
    for (int m = 0; m < 48; m++) s += Ds[h * 48 + m] * Ts[m * 48 + w];
    Fi[i] = s;
  }
}

// ---------------- fused QKV projection ----------------
// blockIdx.y: 0,1 -> Q (fp32 out) ; 2,3 -> K (bf16 out) ; 4,5 -> V (bf16 out)
__global__ __launch_bounds__(256) void k_proj_qkv(
    const float* __restrict__ freq, const float* __restrict__ SF,
    const float* __restrict__ Wq, const float* __restrict__ bq,
    const float* __restrict__ Wk, const float* __restrict__ bk,
    const float* __restrict__ Wv, const float* __restrict__ bv,
    float* __restrict__ Qo, __bf16* __restrict__ Ko, __bf16* __restrict__ Vo){
  const int L = L_TOT, C = C_TOT;
  int proj = blockIdx.y >> 1;
  int m0 = (blockIdx.y & 1) * 64;
  int b = blockIdx.z;
  const float* X   = (proj == 0) ? freq : SF;
  const float* W   = (proj == 0) ? Wq : (proj == 1 ? Wk : Wv);
  const float* bias= (proj == 0) ? bq : (proj == 1 ? bk : bv);
  const float* Xb = X + (size_t)b * C * L;
  int n0 = blockIdx.x * 64;
  __shared__ __align__(16) float As[16][64];
  __shared__ __align__(16) float Bs[16][64];
  int tid = threadIdx.x;
  int tx = tid & 15, ty = tid >> 4;
  float acc[4][4] = {};
  for (int k0 = 0; k0 < C; k0 += 16){
    __syncthreads();
    for (int i = tid; i < 1024; i += 256){
      int m = i & 63, k = i >> 6;
      As[k][m] = W[(size_t)(m0 + m) * C + k0 + k];
    }
    for (int i = tid; i < 1024; i += 256){
      int n = i & 63, k = i >> 6;
      Bs[k][n] = Xb[(size_t)(k0 + k) * L + n0 + n];
    }
    __syncthreads();
    #pragma unroll
    for (int k = 0; k < 16; k++){
      float4 a  = *(const float4*)&As[k][ty * 4];
      float4 bv4 = *(const float4*)&Bs[k][tx * 4];
      float av[4] = {a.x, a.y, a.z, a.w};
      float bb[4] = {bv4.x, bv4.y, bv4.z, bv4.w};
      #pragma unroll
      for (int i2 = 0; i2 < 4; i2++)
        #pragma unroll
        for (int j2 = 0; j2 < 4; j2++)
          acc[i2][j2] += av[i2] * bb[j2];
    }
  }
  if (proj == 0){
    float* Yb = Qo + (size_t)b * C * L;
    #pragma unroll
    for (int i2 = 0; i2 < 4; i2++){
      int o = m0 + ty * 4 + i2;
      float bo = bias[o];
      float4 r;
      r.x = acc[i2][0] + bo; r.y = acc[i2][1] + bo;
      r.z = acc[i2][2] + bo; r.w = acc[i2][3] + bo;
      *(float4*)&Yb[(size_t)o * L + n0 + tx * 4] = r;
    }
  } else {
    __bf16* Yb = ((proj == 1) ? Ko : Vo) + (size_t)b * C * L;
    #pragma unroll
    for (int i2 = 0; i2 < 4; i2++){
      int o = m0 + ty * 4 + i2;
      float bo = bias[o];
      v4bf r;
      r[0] = (__bf16)(acc[i2][0] + bo); r[1] = (__bf16)(acc[i2][1] + bo);
      r[2] = (__bf16)(acc[i2][2] + bo); r[3] = (__bf16)(acc[i2][3] + bo);
      *(v4bf*)&Yb[(size_t)o * L + n0 + tx * 4] = r;
    }
  }
}

// ---------------- fp32 projection (for Wo epilogue) ----------------
__global__ __launch_bounds__(256) void k_proj(const float* __restrict__ W,
                                              const float* __restrict__ bias,
                                              const float* __restrict__ X,
                                              float* __restrict__ Y){
  const int L = L_TOT, C = C_TOT;
  int b = blockIdx.z;
  const float* Xb = X + (size_t)b * C * L;
  float* Yb = Y + (size_t)b * C * L;
  int n0 = blockIdx.x * 64, m0 = blockIdx.y * 64;
  __shared__ __align__(16) float As[16][64];
  __shared__ __align__(16) float Bs[16][64];
  int tid = threadIdx.x;
  int tx = tid & 15, ty = tid >> 4;
  float acc[4][4] = {};
  for (int k0 = 0; k0 < C; k0 += 16){
    __syncthreads();
    for (int i = tid; i < 1024; i += 256){
      int m = i & 63, k = i >> 6;
      As[k][m] = W[(size_t)(m0 + m) * C + k0 + k];
    }
    for (int i = tid; i < 1024; i += 256){
      int n = i & 63, k = i >> 6;
      Bs[k][n] = Xb[(size_t)(k0 + k) * L + n0 + n];
    }
    __syncthreads();
    #pragma unroll
    for (int k = 0; k < 16; k++){
      float4 a  = *(const float4*)&As[k][ty * 4];
      float4 bv4 = *(const float4*)&Bs[k][tx * 4];
      float av[4] = {a.x, a.y, a.z, a.w};
      float bb[4] = {bv4.x, bv4.y, bv4.z, bv4.w};
      #pragma unroll
      for (int i2 = 0; i2 < 4; i2++)
        #pragma unroll
        for (int j2 = 0; j2 < 4; j2++)
          acc[i2][j2] += av[i2] * bb[j2];
    }
  }
  #pragma unroll
  for (int i2 = 0; i2 < 4; i2++){
    int o = m0 + ty * 4 + i2;
    float bo = bias[o];
    float4 r;
    r.x = acc[i2][0] + bo; r.y = acc[i2][1] + bo;
    r.z = acc[i2][2] + bo; r.w = acc[i2][3] + bo;
    *(float4*)&Yb[(size_t)o * L + n0 + tx * 4] = r;
  }
}

// ---------------- MFMA flash attention (S^T formulation) ----------------
// Per (b,h): S^T = (K^T)(Q*0.25) via mfma(A=K-frag[s][d-pad32], B=Q-frag[d][l]),
// C/D: col=l (lane&15), row=s (quad*4+reg)  ->  P^T regs are s-consecutive:
// packed b64 write into per-wave Pt[l][s_rel], then out^T += mfma(A=V^T, B=P^T).
// No max-subtraction: scores are O(1) N(0,1)-ish; exp cannot overflow fp32.
__global__ __launch_bounds__(256) void k_attn_mfma(const float* __restrict__ Q,
                                                   const __bf16* __restrict__ K,
                                                   const __bf16* __restrict__ V,
                                                   float* __restrict__ AO){
  const int L = L_TOT;
  int bh = blockIdx.y;
  int b = bh >> 3, h = bh & 7;
  int c0 = h * 16;
  const float*  Qb = Q + ((size_t)b * C_TOT + c0) * L;
  const __bf16* Kb = K + ((size_t)b * C_TOT + c0) * L;
  const __bf16* Vb = V + ((size_t)b * C_TOT + c0) * L;
  int tid = threadIdx.x;
  int wave = tid >> 6, lane = tid & 63;
  int qd = lane >> 4, cn = lane & 15;      // quad, col(l)/row(m) index
  int l0 = blockIdx.x * 64 + wave * 16;

  __shared__ __align__(16) __bf16 Kt[256 * 36];   // [s_local][d] rows 72 B
  __shared__ __align__(16) __bf16 Vs[16 * 264];   // [d][s_local] rows 528 B
  __shared__ __align__(16) __bf16 Pt[4][16 * 40]; // per-wave [l][s_rel] rows 80 B
  __bf16* Ptw = Pt[wave];

  // Q B-frag: B[k=d][n=l], lane n=cn, k=qd*8+j ; quads 2,3 = zero pad (d>=16)
  v8bf qf;
  #pragma unroll
  for (int j = 0; j < 8; j++) qf[j] = (__bf16)0.0f;
  if (qd < 2){
    #pragma unroll
    for (int j = 0; j < 8; j++)
      qf[j] = (__bf16)(Qb[(size_t)(qd * 8 + j) * L + l0 + cn] * 0.25f);
  }

  v4f acc = {0.f, 0.f, 0.f, 0.f};
  float den = 0.f;

  for (int ch = 0; ch < 9; ch++){
    int s0 = ch * 256;
    __syncthreads();
    {
      // stage K transposed: thread <-> s_local
      const __bf16* Kc = Kb + s0 + tid;
      __bf16 kv[16];
      #pragma unroll
      for (int d = 0; d < 16; d++) kv[d] = Kc[(size_t)d * L];
      #pragma unroll
      for (int dq = 0; dq < 4; dq++){
        v4bf w;
        w[0] = kv[dq*4]; w[1] = kv[dq*4+1]; w[2] = kv[dq*4+2]; w[3] = kv[dq*4+3];
        *(v4bf*)&Kt[tid * 36 + dq * 4] = w;
      }
      // stage V direct: d = tid>>4, 16 s per thread
      int d = tid >> 4, og = tid & 15;
      const __bf16* Vc = Vb + (size_t)d * L + s0 + og * 16;
      *(v8bf*)&Vs[d * 264 + og * 16]     = *(const v8bf*)Vc;
      *(v8bf*)&Vs[d * 264 + og * 16 + 8] = *(const v8bf*)(Vc + 8);
    }
    __syncthreads();

    #pragma unroll
    for (int sc = 0; sc < 8; sc++){
      int sb = sc * 32;
      // A-frags: A[m=s][k=d], lane m=cn, k=qd*8+j ; quads 2,3 zero (d pad)
      v8bf a0, a1;
      #pragma unroll
      for (int j = 0; j < 8; j++){ a0[j] = (__bf16)0.0f; a1[j] = (__bf16)0.0f; }
      if (qd < 2){
        const __bf16* r0 = &Kt[(sb + cn) * 36 + qd * 8];
        v4bf lo0 = *(const v4bf*)r0, hi0 = *(const v4bf*)(r0 + 4);
        a0 = __builtin_shufflevector(lo0, hi0, 0, 1, 2, 3, 4, 5, 6, 7);
        const __bf16* r1 = &Kt[(sb + 16 + cn) * 36 + qd * 8];
        v4bf lo1 = *(const v4bf*)r1, hi1 = *(const v4bf*)(r1 + 4);
        a1 = __builtin_shufflevector(lo1, hi1, 0, 1, 2, 3, 4, 5, 6, 7);
      }
      v4f z = {0.f, 0.f, 0.f, 0.f};
      v4f st0 = MFMA_16x16x32_BF16(a0, qf, z);
      v4f st1 = MFMA_16x16x32_BF16(a1, qf, z);
      float p0[4], p1[4];
      #pragma unroll
      for (int i = 0; i < 4; i++){
        p0[i] = __expf(st0[i]); den += p0[i];
        p1[i] = __expf(st1[i]); den += p1[i];
      }
      v4bf w0, w1;
      #pragma unroll
      for (int i = 0; i < 4; i++){ w0[i] = (__bf16)p0[i]; w1[i] = (__bf16)p1[i]; }
      *(v4bf*)&Ptw[cn * 40 + qd * 4]      = w0;   // s_rel = 0*16 + 4*qd + r
      *(v4bf*)&Ptw[cn * 40 + 16 + qd * 4] = w1;   // s_rel = 16   + 4*qd + r
      // PV: A = V^T frag (m=d, k=s_rel), B = P^T frag (k=s_rel, n=l)
      v8bf vf = *(const v8bf*)&Vs[cn * 264 + sb + qd * 8];
      v8bf pf = *(const v8bf*)&Ptw[cn * 40 + qd * 8];
      acc = MFMA_16x16x32_BF16(vf, pf, acc);
    }
  }

  // denominators: sum P over all s per column l=cn -> reduce across quads
  float dt = den + __shfl_xor(den, 16);
  dt += __shfl_xor(dt, 32);
  float inv = 1.0f / dt;
  float* Ao = AO + ((size_t)b * C_TOT + c0) * L;
  #pragma unroll
  for (int r = 0; r < 4; r++)
    Ao[(size_t)(qd * 4 + r) * L + l0 + cn] = acc[r] * inv;
}

extern "C" void kernel_launch(void* const* d_in, const int* in_sizes, int n_in,
                              void* d_out, int out_size, void* d_ws, size_t ws_size,
                              hipStream_t stream){
  const float* freq = (const float*)d_in[0];
  const float* spat = (const float*)d_in[1];
  const float* Wq = (const float*)d_in[2]; const float* bq = (const float*)d_in[3];
  const float* Wk = (const float*)d_in[4]; const float* bk = (const float*)d_in[5];
  const float* Wv = (const float*)d_in[6]; const float* bv = (const float*)d_in[7];
  const float* Wo = (const float*)d_in[8]; const float* bo = (const float*)d_in[9];
  float* ws = (float*)d_ws;

  // workspace (float units): D | SF | Q | AO | Kg(bf16) | Vg(bf16)
  float* D  = ws;                       // 4096
  float* SF = ws + 4096;                // 589824
  float* Qb = ws + 593920;              // 589824
  float* AO = ws + 1183744;             // 589824
  __bf16* Kg = (__bf16*)(ws + 1773568); // 589824 bf16 = 294912 float slots
  __bf16* Vg = (__bf16*)(ws + 2068480); // 589824 bf16
  float* out = (float*)d_out;

  k_build_dct<<<dim3(9), dim3(256), 0, stream>>>(D);
  k_dct2d<<<dim3(256), dim3(256), 0, stream>>>(spat, D, SF);
  k_proj_qkv<<<dim3(36, 6, 2), dim3(256), 0, stream>>>(freq, SF, Wq, bq, Wk, bk, Wv, bv,
                                                       Qb, Kg, Vg);
  k_attn_mfma<<<dim3(36, 16), dim3(256), 0, stream>>>(Qb, Kg, Vg, AO);
  k_proj<<<dim3(36, 2, 2), dim3(256), 0, stream>>>(Wo, bo, AO, out);
}

// Round 3
// 155.853 us; speedup vs baseline: 2.1007x; 1.0986x over previous
//
#include <hip/hip_runtime.h>
#include <math.h>

#define L_TOT 2304
#define C_TOT 128

typedef float v4f  __attribute__((ext_vector_type(4)));
typedef __bf16 v8bf __attribute__((ext_vector_type(8)));
typedef __bf16 v4bf __attribute__((ext_vector_type(4)));

#define MFMA_16x16x32_BF16(A, B, C) __builtin_amdgcn_mfma_f32_16x16x32_bf16((A), (B), (C), 0, 0, 0)

// ---------------- 2D DCT: F = D * X * D^T per (b,c) image ----------------
// D built in-kernel: angle reduced exactly via m = (2n+1)k mod 192, cosf on [0,2pi).
// 3x3 register tile per thread: 6 LDS reads per 9 FMAs (vs 2 per 1 before).
__global__ __launch_bounds__(256) void k_dct2d(const float* __restrict__ X,
                                               float* __restrict__ F){
  __shared__ float Ds[2304];   // D[k][n] row-major
  __shared__ float DTs[2304];  // D^T[n][k]
  __shared__ float Xs[2304];
  __shared__ float Ts[2304];
  const float* Xi = X + (size_t)blockIdx.x * 2304;
  float* Fi = F + (size_t)blockIdx.x * 2304;
  int tid = threadIdx.x;
  for (int i = tid; i < 2304; i += 256){
    int k = i / 48, n = i - k * 48;
    int m = ((2 * n + 1) * k) % 192;
    float v = cosf(0.032724923474893679f * (float)m) * 0.204124145231931508f;
    if (k == 0) v *= 0.707106781186547524f;
    Ds[k * 48 + n] = v;
    DTs[n * 48 + k] = v;
    Xs[i] = Xi[i];
  }
  __syncthreads();
  int tr = (tid >> 4) * 3, tc = (tid & 15) * 3;
  {
    float a[3][3] = {};
    for (int n = 0; n < 48; n++){
      float x0 = Xs[tr * 48 + n], x1 = Xs[(tr + 1) * 48 + n], x2 = Xs[(tr + 2) * 48 + n];
      float d0 = DTs[n * 48 + tc], d1 = DTs[n * 48 + tc + 1], d2 = DTs[n * 48 + tc + 2];
      a[0][0] += x0 * d0; a[0][1] += x0 * d1; a[0][2] += x0 * d2;
      a[1][0] += x1 * d0; a[1][1] += x1 * d1; a[1][2] += x1 * d2;
      a[2][0] += x2 * d0; a[2][1] += x2 * d1; a[2][2] += x2 * d2;
    }
    #pragma unroll
    for (int i = 0; i < 3; i++)
      #pragma unroll
      for (int j = 0; j < 3; j++)
        Ts[(tr + i) * 48 + tc + j] = a[i][j];
  }
  __syncthreads();
  {
    float c[3][3] = {};
    for (int m = 0; m < 48; m++){
      float d0 = Ds[tr * 48 + m], d1 = Ds[(tr + 1) * 48 + m], d2 = Ds[(tr + 2) * 48 + m];
      float t0 = Ts[m * 48 + tc], t1 = Ts[m * 48 + tc + 1], t2 = Ts[m * 48 + tc + 2];
      c[0][0] += d0 * t0; c[0][1] += d0 * t1; c[0][2] += d0 * t2;
      c[1][0] += d1 * t0; c[1][1] += d1 * t1; c[1][2] += d1 * t2;
      c[2][0] += d2 * t0; c[2][1] += d2 * t1; c[2][2] += d2 * t2;
    }
    #pragma unroll
    for (int i = 0; i < 3; i++)
      #pragma unroll
      for (int j = 0; j < 3; j++)
        Fi[(tr + i) * 48 + tc + j] = c[i][j];
  }
}

// ---------------- fused QKV projection ----------------
// blockIdx.y: 0,1 -> Q (fp32 out) ; 2,3 -> K (bf16 out) ; 4,5 -> V (bf16 out)
__global__ __launch_bounds__(256) void k_proj_qkv(
    const float* __restrict__ freq, const float* __restrict__ SF,
    const float* __restrict__ Wq, const float* __restrict__ bq,
    const float* __restrict__ Wk, const float* __restrict__ bk,
    const float* __restrict__ Wv, const float* __restrict__ bv,
    float* __restrict__ Qo, __bf16* __restrict__ Ko, __bf16* __restrict__ Vo){
  const int L = L_TOT, C = C_TOT;
  int proj = blockIdx.y >> 1;
  int m0 = (blockIdx.y & 1) * 64;
  int b = blockIdx.z;
  const float* X   = (proj == 0) ? freq : SF;
  const float* W   = (proj == 0) ? Wq : (proj == 1 ? Wk : Wv);
  const float* bias= (proj == 0) ? bq : (proj == 1 ? bk : bv);
  const float* Xb = X + (size_t)b * C * L;
  int n0 = blockIdx.x * 64;
  __shared__ __align__(16) float As[16][68];   // padded: kills stride-64 write conflict
  __shared__ __align__(16) float Bs[16][64];
  int tid = threadIdx.x;
  int tx = tid & 15, ty = tid >> 4;
  float acc[4][4] = {};
  for (int k0 = 0; k0 < C; k0 += 16){
    __syncthreads();
    for (int i = tid; i < 1024; i += 256){
      int m = i >> 4, k = i & 15;          // k fast -> 64B global segments
      As[k][m] = W[(size_t)(m0 + m) * C + k0 + k];
    }
    for (int i = tid; i < 1024; i += 256){
      int n = i & 63, k = i >> 6;
      Bs[k][n] = Xb[(size_t)(k0 + k) * L + n0 + n];
    }
    __syncthreads();
    #pragma unroll
    for (int k = 0; k < 16; k++){
      float4 a  = *(const float4*)&As[k][ty * 4];
      float4 bv4 = *(const float4*)&Bs[k][tx * 4];
      float av[4] = {a.x, a.y, a.z, a.w};
      float bb[4] = {bv4.x, bv4.y, bv4.z, bv4.w};
      #pragma unroll
      for (int i2 = 0; i2 < 4; i2++)
        #pragma unroll
        for (int j2 = 0; j2 < 4; j2++)
          acc[i2][j2] += av[i2] * bb[j2];
    }
  }
  if (proj == 0){
    float* Yb = Qo + (size_t)b * C * L;
    #pragma unroll
    for (int i2 = 0; i2 < 4; i2++){
      int o = m0 + ty * 4 + i2;
      float bo = bias[o];
      float4 r;
      r.x = acc[i2][0] + bo; r.y = acc[i2][1] + bo;
      r.z = acc[i2][2] + bo; r.w = acc[i2][3] + bo;
      *(float4*)&Yb[(size_t)o * L + n0 + tx * 4] = r;
    }
  } else {
    __bf16* Yb = ((proj == 1) ? Ko : Vo) + (size_t)b * C * L;
    #pragma unroll
    for (int i2 = 0; i2 < 4; i2++){
      int o = m0 + ty * 4 + i2;
      float bo = bias[o];
      v4bf r;
      r[0] = (__bf16)(acc[i2][0] + bo); r[1] = (__bf16)(acc[i2][1] + bo);
      r[2] = (__bf16)(acc[i2][2] + bo); r[3] = (__bf16)(acc[i2][3] + bo);
      *(v4bf*)&Yb[(size_t)o * L + n0 + tx * 4] = r;
    }
  }
}

// ---------------- fp32 projection (Wo epilogue) ----------------
__global__ __launch_bounds__(256) void k_proj(const float* __restrict__ W,
                                              const float* __restrict__ bias,
                                              const float* __restrict__ X,
                                              float* __restrict__ Y){
  const int L = L_TOT, C = C_TOT;
  int b = blockIdx.z;
  const float* Xb = X + (size_t)b * C * L;
  float* Yb = Y + (size_t)b * C * L;
  int n0 = blockIdx.x * 64, m0 = blockIdx.y * 64;
  __shared__ __align__(16) float As[16][68];
  __shared__ __align__(16) float Bs[16][64];
  int tid = threadIdx.x;
  int tx = tid & 15, ty = tid >> 4;
  float acc[4][4] = {};
  for (int k0 = 0; k0 < C; k0 += 16){
    __syncthreads();
    for (int i = tid; i < 1024; i += 256){
      int m = i >> 4, k = i & 15;
      As[k][m] = W[(size_t)(m0 + m) * C + k0 + k];
    }
    for (int i = tid; i < 1024; i += 256){
      int n = i & 63, k = i >> 6;
      Bs[k][n] = Xb[(size_t)(k0 + k) * L + n0 + n];
    }
    __syncthreads();
    #pragma unroll
    for (int k = 0; k < 16; k++){
      float4 a  = *(const float4*)&As[k][ty * 4];
      float4 bv4 = *(const float4*)&Bs[k][tx * 4];
      float av[4] = {a.x, a.y, a.z, a.w};
      float bb[4] = {bv4.x, bv4.y, bv4.z, bv4.w};
      #pragma unroll
      for (int i2 = 0; i2 < 4; i2++)
        #pragma unroll
        for (int j2 = 0; j2 < 4; j2++)
          acc[i2][j2] += av[i2] * bb[j2];
    }
  }
  #pragma unroll
  for (int i2 = 0; i2 < 4; i2++){
    int o = m0 + ty * 4 + i2;
    float bo = bias[o];
    float4 r;
    r.x = acc[i2][0] + bo; r.y = acc[i2][1] + bo;
    r.z = acc[i2][2] + bo; r.w = acc[i2][3] + bo;
    *(float4*)&Yb[(size_t)o * L + n0 + tx * 4] = r;
  }
}

// ---------------- MFMA flash attention (S^T formulation, s-split waves) ----------------
// Block: 64 l-columns of one (b,h). Wave w owns s-subrange [w*64, w*64+64) of each
// 256-s chunk, computing ALL 4 l-tiles (a-frags + V-frag amortized over 4 tiles).
// Legal because softmax-without-max is a pure sum over s: acc/den from disjoint
// s-ranges add linearly; cross-wave combine once at the end via LDS.
// C/D: col=l (lane&15), row=s (quad*4+reg) -> P^T regs s-consecutive: b64 writes.
__global__ __launch_bounds__(256) void k_attn_mfma(const float* __restrict__ Q,
                                                   const __bf16* __restrict__ K,
                                                   const __bf16* __restrict__ V,
                                                   float* __restrict__ AO){
  const int L = L_TOT;
  int bh = blockIdx.y;
  int b = bh >> 3, h = bh & 7;
  int c0 = h * 16;
  const float*  Qb = Q + ((size_t)b * C_TOT + c0) * L;
  const __bf16* Kb = K + ((size_t)b * C_TOT + c0) * L;
  const __bf16* Vb = V + ((size_t)b * C_TOT + c0) * L;
  int tid = threadIdx.x;
  int wave = tid >> 6, lane = tid & 63;
  int qd = lane >> 4, cn = lane & 15;
  int l0 = blockIdx.x * 64;

  // smem (bf16 units): Kt[256][36] | Vs[16][264] | Pt[4 waves][4 tiles][16*40]
  __shared__ __align__(16) __bf16 smem[9216 + 4224 + 10240];
  __bf16* Kt = smem;
  __bf16* Vs = smem + 9216;
  __bf16* Pt = smem + 9216 + 4224;

  // Q B-frags for 4 l-tiles: B[k=d][n=l], n=cn, k=qd*8+j ; quads 2,3 zero (d pad)
  v8bf qf[4];
  #pragma unroll
  for (int t = 0; t < 4; t++){
    #pragma unroll
    for (int j = 0; j < 8; j++) qf[t][j] = (__bf16)0.0f;
  }
  if (qd < 2){
    #pragma unroll
    for (int t = 0; t < 4; t++)
      #pragma unroll
      for (int j = 0; j < 8; j++)
        qf[t][j] = (__bf16)(Qb[(size_t)(qd * 8 + j) * L + l0 + t * 16 + cn] * 0.25f);
  }

  v4f acc[4];
  float den[4] = {0.f, 0.f, 0.f, 0.f};
  #pragma unroll
  for (int t = 0; t < 4; t++) acc[t] = (v4f){0.f, 0.f, 0.f, 0.f};

  for (int ch = 0; ch < 9; ch++){
    int s0 = ch * 256;
    __syncthreads();
    {
      // stage K transposed: thread <-> s_local (coalesced 128B/instr across lanes)
      const __bf16* Kc = Kb + s0 + tid;
      __bf16 kv[16];
      #pragma unroll
      for (int d = 0; d < 16; d++) kv[d] = Kc[(size_t)d * L];
      #pragma unroll
      for (int dq = 0; dq < 4; dq++){
        v4bf w;
        w[0] = kv[dq*4]; w[1] = kv[dq*4+1]; w[2] = kv[dq*4+2]; w[3] = kv[dq*4+3];
        *(v4bf*)&Kt[tid * 36 + dq * 4] = w;
      }
      // stage V direct
      int dd = tid >> 4, og = tid & 15;
      const __bf16* Vc = Vb + (size_t)dd * L + s0 + og * 16;
      *(v8bf*)&Vs[dd * 264 + og * 16]     = *(const v8bf*)Vc;
      *(v8bf*)&Vs[dd * 264 + og * 16 + 8] = *(const v8bf*)(Vc + 8);
    }
    __syncthreads();

    #pragma unroll
    for (int par = 0; par < 2; par++){
      int sb = wave * 64 + par * 32;
      v8bf a0, a1;
      #pragma unroll
      for (int j = 0; j < 8; j++){ a0[j] = (__bf16)0.0f; a1[j] = (__bf16)0.0f; }
      if (qd < 2){
        const __bf16* r0 = &Kt[(sb + cn) * 36 + qd * 8];
        v4bf lo0 = *(const v4bf*)r0, hi0 = *(const v4bf*)(r0 + 4);
        a0 = __builtin_shufflevector(lo0, hi0, 0, 1, 2, 3, 4, 5, 6, 7);
        const __bf16* r1 = &Kt[(sb + 16 + cn) * 36 + qd * 8];
        v4bf lo1 = *(const v4bf*)r1, hi1 = *(const v4bf*)(r1 + 4);
        a1 = __builtin_shufflevector(lo1, hi1, 0, 1, 2, 3, 4, 5, 6, 7);
      }
      v8bf vf = *(const v8bf*)&Vs[cn * 264 + sb + qd * 8];
      #pragma unroll
      for (int t = 0; t < 4; t++){
        v4f z = {0.f, 0.f, 0.f, 0.f};
        v4f st0 = MFMA_16x16x32_BF16(a0, qf[t], z);
        v4f st1 = MFMA_16x16x32_BF16(a1, qf[t], z);
        float p0[4], p1[4];
        #pragma unroll
        for (int i = 0; i < 4; i++){
          p0[i] = __expf(st0[i]); den[t] += p0[i];
          p1[i] = __expf(st1[i]); den[t] += p1[i];
        }
        v4bf w0, w1;
        #pragma unroll
        for (int i = 0; i < 4; i++){ w0[i] = (__bf16)p0[i]; w1[i] = (__bf16)p1[i]; }
        __bf16* Ptw = Pt + (wave * 4 + t) * 640;
        *(v4bf*)&Ptw[cn * 40 + qd * 4]      = w0;
        *(v4bf*)&Ptw[cn * 40 + 16 + qd * 4] = w1;
        v8bf pf = *(const v8bf*)&Ptw[cn * 40 + qd * 8];
        acc[t] = MFMA_16x16x32_BF16(vf, pf, acc[t]);
      }
    }
  }

  // ---- cross-wave combine: waves hold disjoint s-ranges of every l-tile ----
  __syncthreads();
  float* redA = (float*)smem;             // 4*4*64*4 floats = 16384 B (fits in Kt)
  float* redD = (float*)(smem + 9216);    // 4*4*64 floats = 4096 B (fits in Vs)
  #pragma unroll
  for (int t = 0; t < 4; t++){
    *(v4f*)&redA[((wave * 4 + t) * 64 + lane) * 4] = acc[t];
    redD[(wave * 4 + t) * 64 + lane] = den[t];
  }
  __syncthreads();
  {
    int t = wave;   // wave w finalizes l-tile w
    v4f a = (v4f){0.f, 0.f, 0.f, 0.f};
    float dn = 0.f;
    #pragma unroll
    for (int w2 = 0; w2 < 4; w2++){
      v4f x = *(const v4f*)&redA[((w2 * 4 + t) * 64 + lane) * 4];
      a[0] += x[0]; a[1] += x[1]; a[2] += x[2]; a[3] += x[3];
      dn += redD[(w2 * 4 + t) * 64 + lane];
    }
    dn += __shfl_xor(dn, 16);
    dn += __shfl_xor(dn, 32);
    float inv = 1.0f / dn;
    float* Ao = AO + ((size_t)b * C_TOT + c0) * L;
    #pragma unroll
    for (int r = 0; r < 4; r++)
      Ao[(size_t)(qd * 4 + r) * L + l0 + t * 16 + cn] = a[r] * inv;
  }
}

extern "C" void kernel_launch(void* const* d_in, const int* in_sizes, int n_in,
                              void* d_out, int out_size, void* d_ws, size_t ws_size,
                              hipStream_t stream){
  const float* freq = (const float*)d_in[0];
  const float* spat = (const float*)d_in[1];
  const float* Wq = (const float*)d_in[2]; const float* bq = (const float*)d_in[3];
  const float* Wk = (const float*)d_in[4]; const float* bk = (const float*)d_in[5];
  const float* Wv = (const float*)d_in[6]; const float* bv = (const float*)d_in[7];
  const float* Wo = (const float*)d_in[8]; const float* bo = (const float*)d_in[9];
  float* ws = (float*)d_ws;

  // workspace (float units): SF | Q | AO | Kg(bf16) | Vg(bf16)
  float* SF = ws;                       // 589824
  float* Qb = ws + 589824;
  float* AO = ws + 1179648;
  __bf16* Kg = (__bf16*)(ws + 1769472); // 589824 bf16
  __bf16* Vg = (__bf16*)(ws + 2064384);
  float* out = (float*)d_out;

  k_dct2d<<<dim3(256), dim3(256), 0, stream>>>(spat, SF);
  k_proj_qkv<<<dim3(36, 6, 2), dim3(256), 0, stream>>>(freq, SF, Wq, bq, Wk, bk, Wv, bv,
                                                       Qb, Kg, Vg);
  k_attn_mfma<<<dim3(36, 16), dim3(256), 0, stream>>>(Qb, Kg, Vg, AO);
  k_proj<<<dim3(36, 2, 2), dim3(256), 0, stream>>>(Wo, bo, AO, out);
}